// Round 22
// baseline (268.632 us; speedup 1.0000x reference)
//
#include <hip/hip_runtime.h>
#include <hip/hip_bf16.h>

typedef __attribute__((ext_vector_type(4))) float f32x4;
typedef __attribute__((ext_vector_type(8))) __bf16 bf16x8;

#define B_    2
#define S_    2048
#define HID_  2048
#define H_    16
#define HD_   128
#define M_    (B_*S_)    // 4096
#define NQKV_ 6144
#define LN10000_OVER16 0.5756462732485114f
#define QSCALE 0.08838834764831845f   // 1/sqrt(128), folded into Q at QKV epilogue

#define GLD16(gp, lp) \
  __builtin_amdgcn_global_load_lds((const __attribute__((address_space(1))) void*)(gp), \
                                   (__attribute__((address_space(3))) void*)(lp), 16, 0, 0)

// ---------------- f32 -> bf16 flat convert (vectorized) ----------------
__global__ __launch_bounds__(256) void k_cvt_bf16(const float* __restrict__ x,
                                                  __hip_bfloat16* __restrict__ y, int n4) {
  int i = blockIdx.x * 256 + threadIdx.x;
  if (i >= n4) return;
  float4 v = ((const float4*)x)[i];
  union { __hip_bfloat16 h[4]; uint2 u; } o;
  o.h[0] = __float2bfloat16(v.x); o.h[1] = __float2bfloat16(v.y);
  o.h[2] = __float2bfloat16(v.z); o.h[3] = __float2bfloat16(v.w);
  *(uint2*)(y + 4*(size_t)i) = o.u;
}

// ------- W [K][N] f32 -> Wt [N][K] bf16, both weights in one launch (z-indexed) -------
__global__ __launch_bounds__(256) void k_transpose_w2(
    const float* __restrict__ W0, __hip_bfloat16* __restrict__ Wt0, int N0,
    const float* __restrict__ W1, __hip_bfloat16* __restrict__ Wt1, int N1) {
  __shared__ float tile[32][33];
  const float* W = blockIdx.z ? W1 : W0;
  __hip_bfloat16* Wt = blockIdx.z ? Wt1 : Wt0;
  const int N = blockIdx.z ? N1 : N0;
  int k0 = blockIdx.x * 32, n0 = blockIdx.y * 32;
  if (n0 >= N) return;
  int tx = threadIdx.x, ty = threadIdx.y;  // 32 x 8
  #pragma unroll
  for (int i = 0; i < 4; ++i)
    tile[ty + i*8][tx] = W[(size_t)(k0 + ty + i*8)*N + n0 + tx];
  __syncthreads();
  #pragma unroll
  for (int i = 0; i < 4; ++i)
    Wt[(size_t)(n0 + ty + i*8)*HID_ + k0 + tx] = __float2bfloat16(tile[tx][ty + i*8]);
}

// ======== 128x256 BK=64 double-buffered GEMM, __syncthreads-only (r14/r19 proven) ========
// One full __syncthreads per K-tile; airtight. EPI==0 writes V TRANSPOSED (r15).
// BK=32 (r20) traded barriers for occupancy at net loss — BK=64 is the local optimum.
// Reg note: unified VGPR+AGPR pool 512/lane -> do NOT force >2 waves/SIMD (r4 spill).

#define SA_(kt, boff) do {                                                       \
    _Pragma("unroll") for (int L_ = 0; L_ < 2; ++L_)                             \
      GLD16(Ab + (size_t)(L_*64 + srow)*HID_ + (kt)*64 + su*8,                   \
            lds + (boff) + L_*8192 + t*16);                                      \
  } while (0)

#define SB_(kt, half, boff) do {                                                 \
    _Pragma("unroll") for (int L_ = 0; L_ < 2; ++L_)                             \
      GLD16(Bb + (size_t)((half)*128 + L_*64 + srow)*HID_ + (kt)*64 + su*8,      \
            lds + (boff) + 16384 + (half)*16384 + L_*8192 + t*16);               \
  } while (0)

#define RDA_(boff) do {                                                          \
    _Pragma("unroll") for (int q_ = 0; q_ < 4; ++q_)                             \
      _Pragma("unroll") for (int ks_ = 0; ks_ < 2; ++ks_)                        \
        af[q_][ks_] = *(const bf16x8*)(lds + (boff) + aBase + q_*2048            \
                                       + (((ks_*4+g) ^ key)*16));                \
  } while (0)

#define RDB_(nh, boff) do {                                                      \
    _Pragma("unroll") for (int n_ = 0; n_ < 2; ++n_)                             \
      _Pragma("unroll") for (int ks_ = 0; ks_ < 2; ++ks_)                        \
        bf[n_][ks_] = *(const bf16x8*)(lds + (boff) + bBase + ((nh)*2+n_)*2048   \
                                       + (((ks_*4+g) ^ key)*16));                \
  } while (0)

#define MM_(nh) do {                                                             \
    _Pragma("unroll") for (int q_ = 0; q_ < 4; ++q_)                             \
      _Pragma("unroll") for (int n_ = 0; n_ < 2; ++n_)                           \
        _Pragma("unroll") for (int ks_ = 0; ks_ < 2; ++ks_)                      \
          acc[q_][(nh)*2+n_] = __builtin_amdgcn_mfma_f32_16x16x32_bf16(          \
              af[q_][ks_], bf[n_][ks_], acc[q_][(nh)*2+n_], 0, 0, 0);            \
  } while (0)

template<int EPI, int BNX>
__global__ __launch_bounds__(512, 2) void k_g2(
    const __hip_bfloat16* __restrict__ A,
    const __hip_bfloat16* __restrict__ Bt,
    const float* __restrict__ bias,
    const int* __restrict__ pos_ids,
    __hip_bfloat16* __restrict__ Qb,
    __hip_bfloat16* __restrict__ Kb,
    __hip_bfloat16* __restrict__ VTb,
    float* __restrict__ outF) {
  extern __shared__ char lds[];   // 98304 B: 2 bufs x {A 16K, B 32K}
  const int nk = HID_ / 64;       // 32
  const int t = threadIdx.x, lane = t & 63, g = lane >> 4, c = lane & 15;
  const int w = t >> 6, wr = w >> 2, wc = w & 3;

  const int bid = blockIdx.x;
  const int xcd = bid & 7, idx = bid >> 3;
  const int bn = xcd * BNX + idx % BNX;
  const int bm = idx / BNX;

  const __hip_bfloat16* Ab = A  + (size_t)bm * 128 * HID_;
  const __hip_bfloat16* Bb = Bt + (size_t)bn * 256 * HID_;

  const int srow = t >> 3;                 // 0..63
  const int su   = (t & 7) ^ (srow & 7);   // pre-swizzled source unit
  const int aBase = (wr*64 + c) * 128;
  const int bBase = 16384 + (wc*64 + c) * 128;
  const int key = c & 7;

  f32x4 acc[4][4] = {};
  bf16x8 af[4][2], bf[2][2];

  // ---- prologue: tile 0 -> buf0 ----
  SA_(0, 0); SB_(0, 0, 0); SB_(0, 1, 0);
  __syncthreads();   // full drain: tile 0 resident

  for (int kt = 0; kt < nk; ++kt) {
    const int cb = (kt & 1) * 49152;
    const int nb = cb ^ 49152;

    if (kt + 1 < nk) { SA_(kt + 1, nb); SB_(kt + 1, 0, nb); SB_(kt + 1, 1, nb); }

    RDA_(cb); RDB_(0, cb);
    __builtin_amdgcn_s_setprio(1);
    MM_(0);
    __builtin_amdgcn_s_setprio(0);
    RDB_(1, cb);
    __builtin_amdgcn_s_setprio(1);
    MM_(1);
    __builtin_amdgcn_s_setprio(0);

    __syncthreads();   // staged loads landed; all reads of cb retired
  }

  if (EPI == 0) {
    #pragma unroll
    for (int mi = 0; mi < 4; ++mi) {
      const int m0 = bm*128 + wr*64 + mi*16 + g*4;   // multiple of 4
      #pragma unroll
      for (int ni = 0; ni < 4; ++ni) {
        const int n = bn*256 + wc*64 + ni*16 + c;
        const int h = n / 384;
        const int r = n - h*384;
        const int typ = r >> 7;       // 0=q 1=k 2=v (wave-uniform per frag)
        const int d = r & 127;
        if (typ == 2) {
          // fused V^T write: VTb[bh][d][s0..s0+3], 8B packed store (8-aligned)
          const float bv = bias[n];
          union { __hip_bfloat16 hh[4]; uint2 u2; } pk;
          #pragma unroll
          for (int j = 0; j < 4; ++j) pk.hh[j] = __float2bfloat16(acc[mi][ni][j] + bv);
          const int b = m0 >> 11, s0 = m0 & 2047;
          *(uint2*)(VTb + ((size_t)(b*H_ + h)*HD_ + d)*S_ + s0) = pk.u2;
        } else {
          __hip_bfloat16* op = typ ? Kb : Qb;
          const float qs = typ ? 1.0f : QSCALE;   // fold 1/sqrt(HD) into Q
          if (d < 16) {               // rot low half; partner (d+16) is frag ni+1
            const float b0 = bias[n], b1 = bias[n + 16];
            const float invf = __expf(-(float)d * LN10000_OVER16);
            #pragma unroll
            for (int j = 0; j < 4; ++j) {
              int m = m0 + j; int b = m >> 11, s = m & 2047;
              float ang = (float)pos_ids[m] * invf;
              float sv, cv; sincosf(ang, &sv, &cv);
              float x1 = (acc[mi][ni][j] + b0) * qs, x2 = (acc[mi][ni + 1][j] + b1) * qs;
              size_t rb = ((size_t)(b*H_ + h)*S_ + s)*HD_;
              op[rb + d]      = __float2bfloat16(x1*cv - x2*sv);
              op[rb + d + 16] = __float2bfloat16(x2*cv + x1*sv);
            }
          } else if (d >= 32) {       // pass-through
            const float bv = bias[n];
            #pragma unroll
            for (int j = 0; j < 4; ++j) {
              int m = m0 + j; int b = m >> 11, s = m & 2047;
              op[((size_t)(b*H_ + h)*S_ + s)*HD_ + d] = __float2bfloat16((acc[mi][ni][j] + bv) * qs);
            }
          } // 16 <= d < 32: written by partner frag
        }
      }
    }
  } else {
    #pragma unroll
    for (int mi = 0; mi < 4; ++mi) {
      const int m0 = bm*128 + wr*64 + mi*16 + g*4;
      #pragma unroll
      for (int ni = 0; ni < 4; ++ni) {
        const int n = bn*256 + wc*64 + ni*16 + c;
        const float bv = bias[n];
        #pragma unroll
        for (int j = 0; j < 4; ++j) {
          int m = m0 + j;
          outF[(size_t)m*HID_ + n] = acc[mi][ni][j] + bv;
        }
      }
    }
  }
}

// ---- flash attention: swapped QK^T, 256 q-rows/block, 8 waves (r22) ----
// grid (32 bh, 8): qt = 7 - y (heavy-first), block covers rows qt*256 .. +255,
// 8 waves x 32 rows. Per-wave code identical to r21 (mi in {0,1}, same fragments,
// same P layout 4K/wave). Staged K/V tile now feeds 2x the MFMA -> staging bytes
// and barriers per unit work halve; grid 256 = 1 generation, makespan 32 tiles.
// LDS 96 KiB: K/V dbuf @0/@32768 (32K each), per-wave P @65536 (8 x 4K).
#define ASTG(kt, boff) do {                                                      \
    _Pragma("unroll")                                                            \
    for (int i_ = 0; i_ < 2; ++i_) {                                             \
      int idx_ = i_*512 + t;                                                     \
      int row_ = idx_ >> 4, u_ = idx_ & 15;                                      \
      GLD16(Kp + (size_t)((kt)*64 + row_)*HD_ + ((u_ ^ (row_ & 15)) * 8),        \
            lds + (boff) + idx_*16);                                             \
    }                                                                            \
    _Pragma("unroll")                                                            \
    for (int i_ = 0; i_ < 2; ++i_) {                                             \
      int idx_ = i_*512 + t;                                                     \
      int dr_ = idx_ >> 3, u_ = idx_ & 7;                                        \
      GLD16(Vp + (size_t)dr_*S_ + (kt)*64 + ((u_ ^ (dr_ & 7)) * 8),              \
            lds + (boff) + 16384 + idx_*16);                                     \
    }                                                                            \
  } while (0)

__global__ __launch_bounds__(512) void k_attn(
    const __hip_bfloat16* __restrict__ Qb,
    const __hip_bfloat16* __restrict__ Kb,
    const __hip_bfloat16* __restrict__ VTb,
    __hip_bfloat16* __restrict__ Ob) {
  extern __shared__ char lds[];   // 98304
  const int t = threadIdx.x, lane = t & 63, w = t >> 6, g = lane >> 4, c = lane & 15;
  char* lPw = lds + 65536 + w * 4096;
  const int bh = blockIdx.x, qt = 7 - blockIdx.y;  // heavy blocks dispatch first
  const size_t base = (size_t)bh * S_ * HD_;
  const __hip_bfloat16* Qp = Qb + base;
  const __hip_bfloat16* Kp = Kb + base;
  const __hip_bfloat16* Vp = VTb + base;

  bf16x8 qf[2][4];
  #pragma unroll
  for (int mi = 0; mi < 2; ++mi) {
    int qrow = qt*256 + w*32 + mi*16 + c;
    #pragma unroll
    for (int kf = 0; kf < 4; ++kf)
      qf[mi][kf] = *(const bf16x8*)(Qp + (size_t)qrow*HD_ + kf*32 + g*8);
  }

  f32x4 oacc[2][8] = {};
  float mrun[2] = {-3.0e38f, -3.0e38f};
  float lpart[2] = {0.f, 0.f};

  const int nkt = qt*4 + 4;

  // prologue: tile 0 -> buf0 (barrier also drains the Q register loads)
  ASTG(0, 0);
  __syncthreads();

  for (int kt = 0; kt < nkt; ++kt) {
    const int cur = (kt & 1) * 32768;
    const int nxt = cur ^ 32768;
    if (kt + 1 < nkt) ASTG(kt + 1, nxt);   // flies over this tile's compute

    // ---- S^T = K Q^T (swapped operands; Q pre-scaled) ----
    // sacc[mi][ni][j]: q = qt*256+w*32+mi*16+c,  k = kt*64 + ni*16 + g*4 + j
    f32x4 sacc[2][4] = {};
    #pragma unroll
    for (int ni = 0; ni < 4; ++ni) {
      int krow = ni*16 + c;
      bf16x8 kfr[4];
      #pragma unroll
      for (int kf = 0; kf < 4; ++kf)
        kfr[kf] = *(const bf16x8*)(lds + cur + krow*256 + (((kf*4 + g) ^ (krow & 15)) * 16));
      #pragma unroll
      for (int mi = 0; mi < 2; ++mi)
        #pragma unroll
        for (int kf = 0; kf < 4; ++kf)
          sacc[mi][ni] = __builtin_amdgcn_mfma_f32_16x16x32_bf16(kfr[kf], qf[mi][kf], sacc[mi][ni], 0, 0, 0);
    }

    // ---- mask (diagonal tiles only) + lane-local max over this lane's 16 k ----
    float lm[2];
    float tdiff;
    {
      float td = -3.0e38f;
      #pragma unroll
      for (int mi = 0; mi < 2; ++mi) {
        const int rbase = qt*256 + w*32 + mi*16;
        const int qrow = rbase + c;
        if (kt*64 + 63 > rbase) {   // wave-uniform
          #pragma unroll
          for (int ni = 0; ni < 4; ++ni)
            #pragma unroll
            for (int j = 0; j < 4; ++j) {
              int col = kt*64 + ni*16 + g*4 + j;
              if (col > qrow) sacc[mi][ni][j] = -3.0e38f;
            }
        }
        float m = -3.0e38f;
        #pragma unroll
        for (int ni = 0; ni < 4; ++ni)
          m = fmaxf(m, fmaxf(fmaxf(sacc[mi][ni][0], sacc[mi][ni][1]),
                             fmaxf(sacc[mi][ni][2], sacc[mi][ni][3])));
        lm[mi] = m;
        td = fmaxf(td, m - mrun[mi]);
      }
      tdiff = td;
    }

    // ---- defer-max online softmax; P packed -> b64 writes ----
    if (__all(tdiff <= 8.0f)) {
      #pragma unroll
      for (int mi = 0; mi < 2; ++mi) {
        const float mr = mrun[mi];
        const int prow = mi*16 + c;
        float ps = 0.f;
        #pragma unroll
        for (int ni = 0; ni < 4; ++ni) {
          float p0 = __expf(sacc[mi][ni][0] - mr);
          float p1 = __expf(sacc[mi][ni][1] - mr);
          float p2 = __expf(sacc[mi][ni][2] - mr);
          float p3 = __expf(sacc[mi][ni][3] - mr);
          ps += (p0 + p1) + (p2 + p3);
          union { __hip_bfloat162 h; unsigned u; } a, b2;
          a.h  = __float22bfloat162_rn(make_float2(p0, p1));
          b2.h = __float22bfloat162_rn(make_float2(p2, p3));
          *(uint2*)(lPw + prow*128 + (((ni*2 + (g>>1)) ^ (c & 7)) << 4) + (g & 1)*8)
              = make_uint2(a.u, b2.u);
        }
        lpart[mi] += ps;
      }
    } else {
      #pragma unroll
      for (int mi = 0; mi < 2; ++mi) {
        float mx = lm[mi];
        mx = fmaxf(mx, __shfl_xor(mx, 16));
        mx = fmaxf(mx, __shfl_xor(mx, 32));
        float mnew = fmaxf(mrun[mi], mx);
        float fac = __expf(mrun[mi] - mnew);
        mrun[mi] = mnew;
        const int prow = mi*16 + c;
        float ps = 0.f;
        #pragma unroll
        for (int ni = 0; ni < 4; ++ni) {
          float p0 = __expf(sacc[mi][ni][0] - mnew);
          float p1 = __expf(sacc[mi][ni][1] - mnew);
          float p2 = __expf(sacc[mi][ni][2] - mnew);
          float p3 = __expf(sacc[mi][ni][3] - mnew);
          ps += (p0 + p1) + (p2 + p3);
          union { __hip_bfloat162 h; unsigned u; } a, b2;
          a.h  = __float22bfloat162_rn(make_float2(p0, p1));
          b2.h = __float22bfloat162_rn(make_float2(p2, p3));
          *(uint2*)(lPw + prow*128 + (((ni*2 + (g>>1)) ^ (c & 7)) << 4) + (g & 1)*8)
              = make_uint2(a.u, b2.u);
        }
        lpart[mi] = lpart[mi]*fac + ps;
        // rescale oacc rows r = g*4+j with fac of q-row r (source lane: same g, c = r)
        #pragma unroll
        for (int j = 0; j < 4; ++j) {
          float fj = __shfl(fac, (lane & 48) | (g*4 + j));
          #pragma unroll
          for (int nio = 0; nio < 8; ++nio) oacc[mi][nio][j] *= fj;
        }
      }
    }
    // this wave's P writes must land before this wave's P reads (rule #18)
    asm volatile("s_waitcnt lgkmcnt(0)" ::: "memory");
    __builtin_amdgcn_sched_barrier(0);

    // ---- O += P V (reader unchanged) ----
    bf16x8 paf[2][2];
    #pragma unroll
    for (int mi = 0; mi < 2; ++mi)
      #pragma unroll
      for (int kc = 0; kc < 2; ++kc) {
        int prow = mi*16 + c;
        paf[mi][kc] = *(const bf16x8*)(lPw + prow*128 + (((kc*4 + g) ^ (prow & 7)) * 16));
      }
    #pragma unroll
    for (int nio = 0; nio < 8; ++nio) {
      int dr = nio*16 + c;
      bf16x8 v0 = *(const bf16x8*)(lds + cur + 16384 + dr*128 + (((g)     ^ (dr & 7)) * 16));
      bf16x8 v1 = *(const bf16x8*)(lds + cur + 16384 + dr*128 + (((4 + g) ^ (dr & 7)) * 16));
      #pragma unroll
      for (int mi = 0; mi < 2; ++mi) {
        oacc[mi][nio] = __builtin_amdgcn_mfma_f32_16x16x32_bf16(paf[mi][0], v0, oacc[mi][nio], 0, 0, 0);
        oacc[mi][nio] = __builtin_amdgcn_mfma_f32_16x16x32_bf16(paf[mi][1], v1, oacc[mi][nio], 0, 0, 0);
      }
    }

    // ONE full-drain barrier per tile: ASTG(kt+1) landed (vmcnt 0), all waves'
    // ds_reads of cur retired (lgkmcnt 0) -> next iter reads nxt, overwrites cur.
    __syncthreads();
  }

  // ---- epilogue: reduce row-sums (per q=c), broadcast inv to oacc rows, write ----
  const int b = bh >> 4, h = bh & 15;
  #pragma unroll
  for (int mi = 0; mi < 2; ++mi) {
    float ls = lpart[mi];
    ls += __shfl_xor(ls, 16);
    ls += __shfl_xor(ls, 32);
    float inv = 1.0f / ls;
    #pragma unroll
    for (int j = 0; j < 4; ++j) {
      float invj = __shfl(inv, (lane & 48) | (g*4 + j));
      int s = qt*256 + w*32 + mi*16 + g*4 + j;
      size_t rb = ((size_t)(b*S_ + s))*HID_ + h*HD_;
      #pragma unroll
      for (int nio = 0; nio < 8; ++nio)
        Ob[rb + nio*16 + c] = __float2bfloat16(oacc[mi][nio][j] * invj);
    }
  }
}

// ---------------- host launch ----------------
extern "C" void kernel_launch(void* const* d_in, const int* in_sizes, int n_in,
                              void* d_out, int out_size, void* d_ws, size_t ws_size,
                              hipStream_t stream) {
  const float* hs   = (const float*)d_in[0];
  const int*   pos  = (const int*)d_in[1];
  const float* Wqkv = (const float*)d_in[3];
  const float* bqkv = (const float*)d_in[4];
  const float* Wd   = (const float*)d_in[5];
  const float* bd   = (const float*)d_in[6];
  float* out = (float*)d_out;

  char* ws = (char*)d_ws;
  __hip_bfloat16* hsb = (__hip_bfloat16*)(ws);
  __hip_bfloat16* WqT = (__hip_bfloat16*)(ws + 16777216);
  __hip_bfloat16* WdT = (__hip_bfloat16*)(ws + 41943040);
  __hip_bfloat16* Qb  = (__hip_bfloat16*)(ws + 50331648);
  __hip_bfloat16* Kb  = (__hip_bfloat16*)(ws + 67108864);
  __hip_bfloat16* VTb = (__hip_bfloat16*)(ws + 83886080);
  __hip_bfloat16* Ab  = (__hip_bfloat16*)(ws + 100663296);   // attn-out [b][s][hid]

  hipFuncSetAttribute(reinterpret_cast<const void*>(&k_g2<0,3>),
                      hipFuncAttributeMaxDynamicSharedMemorySize, 98304);
  hipFuncSetAttribute(reinterpret_cast<const void*>(&k_g2<1,1>),
                      hipFuncAttributeMaxDynamicSharedMemorySize, 98304);
  hipFuncSetAttribute(reinterpret_cast<const void*>(&k_attn),
                      hipFuncAttributeMaxDynamicSharedMemorySize, 98304);

  k_cvt_bf16<<<8192, 256, 0, stream>>>(hs, hsb, (M_*HID_)/4);
  k_transpose_w2<<<dim3(HID_/32, NQKV_/32, 2), dim3(32, 8), 0, stream>>>(
      Wqkv, WqT, NQKV_, Wd, WdT, HID_);
  // QKV: grid 768 = 32 bm x 24 bn; V written transposed (fused)
  k_g2<0,3><<<768, 512, 98304, stream>>>(hsb, WqT, bqkv, pos, Qb, Kb, VTb, nullptr);
  // attn: 256 blocks (32 bh x 8 qt), 256 q-rows/block, 8 waves
  k_attn<<<dim3(B_*H_, 8), 512, 98304, stream>>>(Qb, Kb, VTb, Ab);
  // dense: grid 256 = 32 bm x 8 bn
  k_g2<1,1><<<256, 512, 98304, stream>>>(Ab, WdT, bd, nullptr, nullptr, nullptr, nullptr, out);
}

// Round 23
// 259.486 us; speedup vs baseline: 1.0352x; 1.0352x over previous
//
#include <hip/hip_runtime.h>
#include <hip/hip_bf16.h>

typedef __attribute__((ext_vector_type(4))) float f32x4;
typedef __attribute__((ext_vector_type(8))) __bf16 bf16x8;

#define B_    2
#define S_    2048
#define HID_  2048
#define H_    16
#define HD_   128
#define M_    (B_*S_)    // 4096
#define NQKV_ 6144
#define LN10000_OVER16 0.5756462732485114f
#define QSCALE 0.08838834764831845f   // 1/sqrt(128), folded into Q at QKV epilogue

#define GLD16(gp, lp) \
  __builtin_amdgcn_global_load_lds((const __attribute__((address_space(1))) void*)(gp), \
                                   (__attribute__((address_space(3))) void*)(lp), 16, 0, 0)

// ---------------- f32 -> bf16 flat convert (vectorized) ----------------
__global__ __launch_bounds__(256) void k_cvt_bf16(const float* __restrict__ x,
                                                  __hip_bfloat16* __restrict__ y, int n4) {
  int i = blockIdx.x * 256 + threadIdx.x;
  if (i >= n4) return;
  float4 v = ((const float4*)x)[i];
  union { __hip_bfloat16 h[4]; uint2 u; } o;
  o.h[0] = __float2bfloat16(v.x); o.h[1] = __float2bfloat16(v.y);
  o.h[2] = __float2bfloat16(v.z); o.h[3] = __float2bfloat16(v.w);
  *(uint2*)(y + 4*(size_t)i) = o.u;
}

// ------- W [K][N] f32 -> Wt [N][K] bf16, both weights in one launch (z-indexed) -------
__global__ __launch_bounds__(256) void k_transpose_w2(
    const float* __restrict__ W0, __hip_bfloat16* __restrict__ Wt0, int N0,
    const float* __restrict__ W1, __hip_bfloat16* __restrict__ Wt1, int N1) {
  __shared__ float tile[32][33];
  const float* W = blockIdx.z ? W1 : W0;
  __hip_bfloat16* Wt = blockIdx.z ? Wt1 : Wt0;
  const int N = blockIdx.z ? N1 : N0;
  int k0 = blockIdx.x * 32, n0 = blockIdx.y * 32;
  if (n0 >= N) return;
  int tx = threadIdx.x, ty = threadIdx.y;  // 32 x 8
  #pragma unroll
  for (int i = 0; i < 4; ++i)
    tile[ty + i*8][tx] = W[(size_t)(k0 + ty + i*8)*N + n0 + tx];
  __syncthreads();
  #pragma unroll
  for (int i = 0; i < 4; ++i)
    Wt[(size_t)(n0 + ty + i*8)*HID_ + k0 + tx] = __float2bfloat16(tile[tx][ty + i*8]);
}

// ======== 128x256 BK=64 double-buffered GEMM, __syncthreads-only (r14/r19 proven) ========
// One full __syncthreads per K-tile; airtight (r10-r13 raw-barrier hazard removed by class).
// EPI==0 writes V TRANSPOSED directly (r15). BK=32 variant (r20) traded barrier count for
// occupancy at net loss — BK=64 is the confirmed local optimum.
// Reg note: unified VGPR+AGPR pool 512/lane -> do NOT force >2 waves/SIMD (r4 spill).

#define SA_(kt, boff) do {                                                       \
    _Pragma("unroll") for (int L_ = 0; L_ < 2; ++L_)                             \
      GLD16(Ab + (size_t)(L_*64 + srow)*HID_ + (kt)*64 + su*8,                   \
            lds + (boff) + L_*8192 + t*16);                                      \
  } while (0)

#define SB_(kt, half, boff) do {                                                 \
    _Pragma("unroll") for (int L_ = 0; L_ < 2; ++L_)                             \
      GLD16(Bb + (size_t)((half)*128 + L_*64 + srow)*HID_ + (kt)*64 + su*8,      \
            lds + (boff) + 16384 + (half)*16384 + L_*8192 + t*16);               \
  } while (0)

#define RDA_(boff) do {                                                          \
    _Pragma("unroll") for (int q_ = 0; q_ < 4; ++q_)                             \
      _Pragma("unroll") for (int ks_ = 0; ks_ < 2; ++ks_)                        \
        af[q_][ks_] = *(const bf16x8*)(lds + (boff) + aBase + q_*2048            \
                                       + (((ks_*4+g) ^ key)*16));                \
  } while (0)

#define RDB_(nh, boff) do {                                                      \
    _Pragma("unroll") for (int n_ = 0; n_ < 2; ++n_)                             \
      _Pragma("unroll") for (int ks_ = 0; ks_ < 2; ++ks_)                        \
        bf[n_][ks_] = *(const bf16x8*)(lds + (boff) + bBase + ((nh)*2+n_)*2048   \
                                       + (((ks_*4+g) ^ key)*16));                \
  } while (0)

#define MM_(nh) do {                                                             \
    _Pragma("unroll") for (int q_ = 0; q_ < 4; ++q_)                             \
      _Pragma("unroll") for (int n_ = 0; n_ < 2; ++n_)                           \
        _Pragma("unroll") for (int ks_ = 0; ks_ < 2; ++ks_)                      \
          acc[q_][(nh)*2+n_] = __builtin_amdgcn_mfma_f32_16x16x32_bf16(          \
              af[q_][ks_], bf[n_][ks_], acc[q_][(nh)*2+n_], 0, 0, 0);            \
  } while (0)

template<int EPI, int BNX>
__global__ __launch_bounds__(512, 2) void k_g2(
    const __hip_bfloat16* __restrict__ A,
    const __hip_bfloat16* __restrict__ Bt,
    const float* __restrict__ bias,
    const int* __restrict__ pos_ids,
    __hip_bfloat16* __restrict__ Qb,
    __hip_bfloat16* __restrict__ Kb,
    __hip_bfloat16* __restrict__ VTb,
    float* __restrict__ outF) {
  extern __shared__ char lds[];   // 98304 B: 2 bufs x {A 16K, B 32K}
  const int nk = HID_ / 64;       // 32
  const int t = threadIdx.x, lane = t & 63, g = lane >> 4, c = lane & 15;
  const int w = t >> 6, wr = w >> 2, wc = w & 3;

  const int bid = blockIdx.x;
  const int xcd = bid & 7, idx = bid >> 3;
  const int bn = xcd * BNX + idx % BNX;
  const int bm = idx / BNX;

  const __hip_bfloat16* Ab = A  + (size_t)bm * 128 * HID_;
  const __hip_bfloat16* Bb = Bt + (size_t)bn * 256 * HID_;

  const int srow = t >> 3;                 // 0..63
  const int su   = (t & 7) ^ (srow & 7);   // pre-swizzled source unit
  const int aBase = (wr*64 + c) * 128;
  const int bBase = 16384 + (wc*64 + c) * 128;
  const int key = c & 7;

  f32x4 acc[4][4] = {};
  bf16x8 af[4][2], bf[2][2];

  // ---- prologue: tile 0 -> buf0 ----
  SA_(0, 0); SB_(0, 0, 0); SB_(0, 1, 0);
  __syncthreads();   // full drain: tile 0 resident

  for (int kt = 0; kt < nk; ++kt) {
    const int cb = (kt & 1) * 49152;
    const int nb = cb ^ 49152;

    if (kt + 1 < nk) { SA_(kt + 1, nb); SB_(kt + 1, 0, nb); SB_(kt + 1, 1, nb); }

    RDA_(cb); RDB_(0, cb);
    __builtin_amdgcn_s_setprio(1);
    MM_(0);
    __builtin_amdgcn_s_setprio(0);
    RDB_(1, cb);
    __builtin_amdgcn_s_setprio(1);
    MM_(1);
    __builtin_amdgcn_s_setprio(0);

    __syncthreads();   // staged loads landed; all reads of cb retired
  }

  if (EPI == 0) {
    #pragma unroll
    for (int mi = 0; mi < 4; ++mi) {
      const int m0 = bm*128 + wr*64 + mi*16 + g*4;   // multiple of 4
      #pragma unroll
      for (int ni = 0; ni < 4; ++ni) {
        const int n = bn*256 + wc*64 + ni*16 + c;
        const int h = n / 384;
        const int r = n - h*384;
        const int typ = r >> 7;       // 0=q 1=k 2=v (wave-uniform per frag)
        const int d = r & 127;
        if (typ == 2) {
          // fused V^T write: VTb[bh][d][s0..s0+3], 8B packed store (8-aligned)
          const float bv = bias[n];
          union { __hip_bfloat16 hh[4]; uint2 u2; } pk;
          #pragma unroll
          for (int j = 0; j < 4; ++j) pk.hh[j] = __float2bfloat16(acc[mi][ni][j] + bv);
          const int b = m0 >> 11, s0 = m0 & 2047;
          *(uint2*)(VTb + ((size_t)(b*H_ + h)*HD_ + d)*S_ + s0) = pk.u2;
        } else {
          __hip_bfloat16* op = typ ? Kb : Qb;
          const float qs = typ ? 1.0f : QSCALE;   // fold 1/sqrt(HD) into Q
          if (d < 16) {               // rot low half; partner (d+16) is frag ni+1
            const float b0 = bias[n], b1 = bias[n + 16];
            const float invf = __expf(-(float)d * LN10000_OVER16);
            #pragma unroll
            for (int j = 0; j < 4; ++j) {
              int m = m0 + j; int b = m >> 11, s = m & 2047;
              float ang = (float)pos_ids[m] * invf;
              float sv, cv; sincosf(ang, &sv, &cv);
              float x1 = (acc[mi][ni][j] + b0) * qs, x2 = (acc[mi][ni + 1][j] + b1) * qs;
              size_t rb = ((size_t)(b*H_ + h)*S_ + s)*HD_;
              op[rb + d]      = __float2bfloat16(x1*cv - x2*sv);
              op[rb + d + 16] = __float2bfloat16(x2*cv + x1*sv);
            }
          } else if (d >= 32) {       // pass-through
            const float bv = bias[n];
            #pragma unroll
            for (int j = 0; j < 4; ++j) {
              int m = m0 + j; int b = m >> 11, s = m & 2047;
              op[((size_t)(b*H_ + h)*S_ + s)*HD_ + d] = __float2bfloat16((acc[mi][ni][j] + bv) * qs);
            }
          } // 16 <= d < 32: written by partner frag
        }
      }
    }
  } else {
    #pragma unroll
    for (int mi = 0; mi < 4; ++mi) {
      const int m0 = bm*128 + wr*64 + mi*16 + g*4;
      #pragma unroll
      for (int ni = 0; ni < 4; ++ni) {
        const int n = bn*256 + wc*64 + ni*16 + c;
        const float bv = bias[n];
        #pragma unroll
        for (int j = 0; j < 4; ++j) {
          int m = m0 + j;
          outF[(size_t)m*HID_ + n] = acc[mi][ni][j] + bv;
        }
      }
    }
  }
}

// ---- flash attention: swapped QK^T + lane-local softmax on r16 airtight structure ----
// grid (B*H, 16). 128 q-rows/block, 4 waves x 32 rows, KVBLK=64, qt = 15-y heavy-first.
// LDS 80 KiB dynamic: K/V dbuf @0/@32768, per-wave P 4K @65536.
// S^T = mfma(K,Q): lane owns q-row (lane&15), 16 k-values (ni,j = k%16 in g*4+j).
// Softmax state: 2 scalars/lane; defer path (T13) has ZERO shuffles; P packs to
// 4 ds_write_b64 per thread per mi. All P traffic same-wave (lgkmcnt + sched_barrier,
// rule #18). r21 proven: 260.2 us, replay-stable. r22's 256-row variant regressed
// (1 block/CU, no scheduling slack) — 128 rows/block is the local optimum both ways.
#define ASTG(kt, boff) do {                                                      \
    _Pragma("unroll")                                                            \
    for (int i_ = 0; i_ < 4; ++i_) {                                             \
      int idx_ = i_*256 + t;                                                     \
      int row_ = idx_ >> 4, u_ = idx_ & 15;                                      \
      GLD16(Kp + (size_t)((kt)*64 + row_)*HD_ + ((u_ ^ (row_ & 15)) * 8),        \
            lds + (boff) + (i_*256 + w*64)*16);                                  \
    }                                                                            \
    _Pragma("unroll")                                                            \
    for (int i_ = 0; i_ < 4; ++i_) {                                             \
      int idx_ = i_*256 + t;                                                     \
      int dr_ = idx_ >> 3, u_ = idx_ & 7;                                        \
      GLD16(Vp + (size_t)dr_*S_ + (kt)*64 + ((u_ ^ (dr_ & 7)) * 8),              \
            lds + (boff) + 16384 + (i_*256 + w*64)*16);                          \
    }                                                                            \
  } while (0)

__global__ __launch_bounds__(256) void k_attn(
    const __hip_bfloat16* __restrict__ Qb,
    const __hip_bfloat16* __restrict__ Kb,
    const __hip_bfloat16* __restrict__ VTb,
    __hip_bfloat16* __restrict__ Ob) {
  extern __shared__ char lds[];   // 81920
  const int t = threadIdx.x, lane = t & 63, w = t >> 6, g = lane >> 4, c = lane & 15;
  char* lPw = lds + 65536 + w * 4096;
  const int bh = blockIdx.x, qt = 15 - blockIdx.y;  // heavy blocks dispatch first
  const size_t base = (size_t)bh * S_ * HD_;
  const __hip_bfloat16* Qp = Qb + base;
  const __hip_bfloat16* Kp = Kb + base;
  const __hip_bfloat16* Vp = VTb + base;

  bf16x8 qf[2][4];
  #pragma unroll
  for (int mi = 0; mi < 2; ++mi) {
    int qrow = qt*128 + w*32 + mi*16 + c;
    #pragma unroll
    for (int kf = 0; kf < 4; ++kf)
      qf[mi][kf] = *(const bf16x8*)(Qp + (size_t)qrow*HD_ + kf*32 + g*8);
  }

  f32x4 oacc[2][8] = {};
  float mrun[2] = {-3.0e38f, -3.0e38f};
  float lpart[2] = {0.f, 0.f};

  const int nkt = qt*2 + 2;

  // prologue: tile 0 -> buf0 (barrier also drains the Q register loads)
  ASTG(0, 0);
  __syncthreads();

  for (int kt = 0; kt < nkt; ++kt) {
    const int cur = (kt & 1) * 32768;
    const int nxt = cur ^ 32768;
    if (kt + 1 < nkt) ASTG(kt + 1, nxt);   // flies over this tile's compute

    // ---- S^T = K Q^T (swapped operands; Q pre-scaled) ----
    // sacc[mi][ni][j]: q = qt*128+w*32+mi*16+c,  k = kt*64 + ni*16 + g*4 + j
    f32x4 sacc[2][4] = {};
    #pragma unroll
    for (int ni = 0; ni < 4; ++ni) {
      int krow = ni*16 + c;
      bf16x8 kfr[4];
      #pragma unroll
      for (int kf = 0; kf < 4; ++kf)
        kfr[kf] = *(const bf16x8*)(lds + cur + krow*256 + (((kf*4 + g) ^ (krow & 15)) * 16));
      #pragma unroll
      for (int mi = 0; mi < 2; ++mi)
        #pragma unroll
        for (int kf = 0; kf < 4; ++kf)
          sacc[mi][ni] = __builtin_amdgcn_mfma_f32_16x16x32_bf16(kfr[kf], qf[mi][kf], sacc[mi][ni], 0, 0, 0);
    }

    // ---- mask (diagonal tiles only) + lane-local max over this lane's 16 k ----
    float lm[2];
    float tdiff;
    {
      float td = -3.0e38f;
      #pragma unroll
      for (int mi = 0; mi < 2; ++mi) {
        const int rbase = qt*128 + w*32 + mi*16;
        const int qrow = rbase + c;
        if (kt*64 + 63 > rbase) {   // wave-uniform
          #pragma unroll
          for (int ni = 0; ni < 4; ++ni)
            #pragma unroll
            for (int j = 0; j < 4; ++j) {
              int col = kt*64 + ni*16 + g*4 + j;
              if (col > qrow) sacc[mi][ni][j] = -3.0e38f;
            }
        }
        float m = -3.0e38f;
        #pragma unroll
        for (int ni = 0; ni < 4; ++ni)
          m = fmaxf(m, fmaxf(fmaxf(sacc[mi][ni][0], sacc[mi][ni][1]),
                             fmaxf(sacc[mi][ni][2], sacc[mi][ni][3])));
        lm[mi] = m;
        td = fmaxf(td, m - mrun[mi]);
      }
      tdiff = td;
    }

    // ---- defer-max online softmax; P packed -> b64 writes ----
    if (__all(tdiff <= 8.0f)) {
      #pragma unroll
      for (int mi = 0; mi < 2; ++mi) {
        const float mr = mrun[mi];
        const int prow = mi*16 + c;
        float ps = 0.f;
        #pragma unroll
        for (int ni = 0; ni < 4; ++ni) {
          float p0 = __expf(sacc[mi][ni][0] - mr);
          float p1 = __expf(sacc[mi][ni][1] - mr);
          float p2 = __expf(sacc[mi][ni][2] - mr);
          float p3 = __expf(sacc[mi][ni][3] - mr);
          ps += (p0 + p1) + (p2 + p3);
          union { __hip_bfloat162 h; unsigned u; } a, b2;
          a.h  = __float22bfloat162_rn(make_float2(p0, p1));
          b2.h = __float22bfloat162_rn(make_float2(p2, p3));
          *(uint2*)(lPw + prow*128 + (((ni*2 + (g>>1)) ^ (c & 7)) << 4) + (g & 1)*8)
              = make_uint2(a.u, b2.u);
        }
        lpart[mi] += ps;
      }
    } else {
      #pragma unroll
      for (int mi = 0; mi < 2; ++mi) {
        float mx = lm[mi];
        mx = fmaxf(mx, __shfl_xor(mx, 16));
        mx = fmaxf(mx, __shfl_xor(mx, 32));
        float mnew = fmaxf(mrun[mi], mx);
        float fac = __expf(mrun[mi] - mnew);
        mrun[mi] = mnew;
        const int prow = mi*16 + c;
        float ps = 0.f;
        #pragma unroll
        for (int ni = 0; ni < 4; ++ni) {
          float p0 = __expf(sacc[mi][ni][0] - mnew);
          float p1 = __expf(sacc[mi][ni][1] - mnew);
          float p2 = __expf(sacc[mi][ni][2] - mnew);
          float p3 = __expf(sacc[mi][ni][3] - mnew);
          ps += (p0 + p1) + (p2 + p3);
          union { __hip_bfloat162 h; unsigned u; } a, b2;
          a.h  = __float22bfloat162_rn(make_float2(p0, p1));
          b2.h = __float22bfloat162_rn(make_float2(p2, p3));
          *(uint2*)(lPw + prow*128 + (((ni*2 + (g>>1)) ^ (c & 7)) << 4) + (g & 1)*8)
              = make_uint2(a.u, b2.u);
        }
        lpart[mi] = lpart[mi]*fac + ps;
        // rescale oacc rows r = g*4+j with fac of q-row r (source lane: same g, c = r)
        #pragma unroll
        for (int j = 0; j < 4; ++j) {
          float fj = __shfl(fac, (lane & 48) | (g*4 + j));
          #pragma unroll
          for (int nio = 0; nio < 8; ++nio) oacc[mi][nio][j] *= fj;
        }
      }
    }
    // this wave's P writes must land before this wave's P reads (rule #18)
    asm volatile("s_waitcnt lgkmcnt(0)" ::: "memory");
    __builtin_amdgcn_sched_barrier(0);

    // ---- O += P V (reader unchanged) ----
    bf16x8 paf[2][2];
    #pragma unroll
    for (int mi = 0; mi < 2; ++mi)
      #pragma unroll
      for (int kc = 0; kc < 2; ++kc) {
        int prow = mi*16 + c;
        paf[mi][kc] = *(const bf16x8*)(lPw + prow*128 + (((kc*4 + g) ^ (prow & 7)) * 16));
      }
    #pragma unroll
    for (int nio = 0; nio < 8; ++nio) {
      int dr = nio*16 + c;
      bf16x8 v0 = *(const bf16x8*)(lds + cur + 16384 + dr*128 + (((g)     ^ (dr & 7)) * 16));
      bf16x8 v1 = *(const bf16x8*)(lds + cur + 16384 + dr*128 + (((4 + g) ^ (dr & 7)) * 16));
      #pragma unroll
      for (int mi = 0; mi < 2; ++mi) {
        oacc[mi][nio] = __builtin_amdgcn_mfma_f32_16x16x32_bf16(paf[mi][0], v0, oacc[mi][nio], 0, 0, 0);
        oacc[mi][nio] = __builtin_amdgcn_mfma_f32_16x16x32_bf16(paf[mi][1], v1, oacc[mi][nio], 0, 0, 0);
      }
    }

    // ONE full-drain barrier per tile: ASTG(kt+1) landed (vmcnt 0), all waves'
    // ds_reads of cur retired (lgkmcnt 0) -> next iter reads nxt, overwrites cur.
    __syncthreads();
  }

  // ---- epilogue: reduce row-sums (per q=c), broadcast inv to oacc rows, write ----
  const int b = bh >> 4, h = bh & 15;
  #pragma unroll
  for (int mi = 0; mi < 2; ++mi) {
    float ls = lpart[mi];
    ls += __shfl_xor(ls, 16);
    ls += __shfl_xor(ls, 32);
    float inv = 1.0f / ls;
    #pragma unroll
    for (int j = 0; j < 4; ++j) {
      float invj = __shfl(inv, (lane & 48) | (g*4 + j));
      int s = qt*128 + w*32 + mi*16 + g*4 + j;
      size_t rb = ((size_t)(b*S_ + s))*HID_ + h*HD_;
      #pragma unroll
      for (int nio = 0; nio < 8; ++nio)
        Ob[rb + nio*16 + c] = __float2bfloat16(oacc[mi][nio][j] * invj);
    }
  }
}

// ---------------- host launch ----------------
extern "C" void kernel_launch(void* const* d_in, const int* in_sizes, int n_in,
                              void* d_out, int out_size, void* d_ws, size_t ws_size,
                              hipStream_t stream) {
  const float* hs   = (const float*)d_in[0];
  const int*   pos  = (const int*)d_in[1];
  const float* Wqkv = (const float*)d_in[3];
  const float* bqkv = (const float*)d_in[4];
  const float* Wd   = (const float*)d_in[5];
  const float* bd   = (const float*)d_in[6];
  float* out = (float*)d_out;

  char* ws = (char*)d_ws;
  __hip_bfloat16* hsb = (__hip_bfloat16*)(ws);
  __hip_bfloat16* WqT = (__hip_bfloat16*)(ws + 16777216);
  __hip_bfloat16* WdT = (__hip_bfloat16*)(ws + 41943040);
  __hip_bfloat16* Qb  = (__hip_bfloat16*)(ws + 50331648);
  __hip_bfloat16* Kb  = (__hip_bfloat16*)(ws + 67108864);
  __hip_bfloat16* VTb = (__hip_bfloat16*)(ws + 83886080);
  __hip_bfloat16* Ab  = (__hip_bfloat16*)(ws + 100663296);   // attn-out [b][s][hid]

  hipFuncSetAttribute(reinterpret_cast<const void*>(&k_g2<0,3>),
                      hipFuncAttributeMaxDynamicSharedMemorySize, 98304);
  hipFuncSetAttribute(reinterpret_cast<const void*>(&k_g2<1,1>),
                      hipFuncAttributeMaxDynamicSharedMemorySize, 98304);
  hipFuncSetAttribute(reinterpret_cast<const void*>(&k_attn),
                      hipFuncAttributeMaxDynamicSharedMemorySize, 81920);

  k_cvt_bf16<<<8192, 256, 0, stream>>>(hs, hsb, (M_*HID_)/4);
  k_transpose_w2<<<dim3(HID_/32, NQKV_/32, 2), dim3(32, 8), 0, stream>>>(
      Wqkv, WqT, NQKV_, Wd, WdT, HID_);
  // QKV: grid 768 = 32 bm x 24 bn; V written transposed (fused)
  k_g2<0,3><<<768, 512, 98304, stream>>>(hsb, WqT, bqkv, pos, Qb, Kb, VTb, nullptr);
  k_attn<<<dim3(B_*H_, 16), 256, 81920, stream>>>(Qb, Kb, VTb, Ab);
  // dense: grid 256 = 32 bm x 8 bn
  k_g2<1,1><<<256, 512, 98304, stream>>>(Ab, WdT, bd, nullptr, nullptr, nullptr, nullptr, out);
}